// Round 11
// baseline (13026.823 us; speedup 1.0000x reference)
//
#include <hip/hip_runtime.h>
#include <stdint.h>

#define NU 4096
#define NB 2048
#define KK2 8192            // i8 bytes per Bt column: 2 levels x 4096
#define ITERS 100
#define CAP 262144
#define THETA 0.05f
#define KC 512              // host fixup k-panel (verified)
#define S1 0.03937007874f   // 5/127 — level-1 quant step
#define S2 (S1 / 254.0f)    // level-2 step; range = S1/2 exactly

// ws layout (bytes) — offsets unchanged
#define OFF_BT   0u
#define OFF_A0   67108864u
#define OFF_A1   83886080u
#define OFF_SUS  100663296u
#define OFF_CNT  102760448u
#define REQ_WS   102761472u

// ROUND-11 — R10 i8 two-level GEMM core VERBATIM + per-row-group convergence
// skipping. Synchronous Hopfield with symmetric zero-diag W converges to
// period<=2 cycles (Goles); rows are independent, grid is tiled by row-group
// (mt = 256 rows). Detection: epilogue compares new sign vs old buffer value
// (= post-fixup A_{t-1}) before overwrite; block -> LDS flag -> one atomicOr
// into bitmask chg[t] (bit mt). fixup sets the bit too when a patch CHANGES
// the stored value (so bit clear <=> raw==old everywhere AND patches no-op
// <=> A_{t+1} == A_{t-1} exactly). Skip: gemm block returns (pre-barrier,
// block-uniform) if bit mt of chg[t-1] clear; bits stay clear forever ->
// permanent skip, buffers frozen in the 2-cycle. A_100 = buffer A0 by parity
// (100 even == todd+1; frozen groups: A_{s+2}=A_s for s>=t0-1). emit kernel
// writes outF once at the end. BIT-EXACT: skips only provably-identical work.
#define NT 64

typedef int i32x4 __attribute__((ext_vector_type(4)));

__device__ __forceinline__ void gl16(const void* g, void* l) {
  __builtin_amdgcn_global_load_lds(
      (const __attribute__((address_space(1))) unsigned int*)g,
      (__attribute__((address_space(3))) unsigned int*)l, 16, 0, 0);
}

__global__ void fill_kernel(float* __restrict__ out, float v) {
  int t = blockIdx.x * blockDim.x + threadIdx.x;
  int base = t << 3;
  float4 a = make_float4(v, v, v, v);
  *(float4*)(out + base) = a;
  *(float4*)(out + base + 4) = a;
}

__device__ __forceinline__ int q127(float x, float s) {
  int v = (int)rintf(x / s);
  return v < -127 ? -127 : (v > 127 ? 127 : v);
}

// W f32 -> two i8 planes: Bt[col*8192 + k] = I1, Bt[col*8192 + 4096 + k] = I2.
__global__ void decompose_kernel(const float* __restrict__ W,
                                 signed char* __restrict__ Bt) {
  int t = blockIdx.x * blockDim.x + threadIdx.x;
  int base = t << 2;
  int j = base >> 12;
  int k = base & 4095;
  float4 w = *(const float4*)(W + (size_t)j * NU + k);
  int a0 = q127(w.x, S1), a1 = q127(w.y, S1), a2 = q127(w.z, S1), a3 = q127(w.w, S1);
  float r0 = w.x - (float)a0 * S1, r1 = w.y - (float)a1 * S1;
  float r2 = w.z - (float)a2 * S1, r3 = w.w - (float)a3 * S1;
  int b0 = q127(r0, S2), b1 = q127(r1, S2), b2 = q127(r2, S2), b3 = q127(r3, S2);
  uchar4 p1 = make_uchar4((unsigned char)a0, (unsigned char)a1,
                          (unsigned char)a2, (unsigned char)a3);
  uchar4 p2 = make_uchar4((unsigned char)b0, (unsigned char)b1,
                          (unsigned char)b2, (unsigned char)b3);
  *(uchar4*)(Bt + (size_t)j * KK2 + k) = p1;
  *(uchar4*)(Bt + (size_t)j * KK2 + 4096 + k) = p2;
}

// Initial state: P (fp32 +-1, exact) -> A0 i8 +-1.
__global__ void init_kernel(const float* __restrict__ P,
                            signed char* __restrict__ A0) {
  int t = blockIdx.x * blockDim.x + threadIdx.x;
  int base = t << 3;
  float4 a = *(const float4*)(P + base);
  float4 b = *(const float4*)(P + base + 4);
  float hv[8] = {a.x, a.y, a.z, a.w, b.x, b.y, b.z, b.w};
  unsigned char s[8];
#pragma unroll
  for (int i = 0; i < 8; ++i) s[i] = (hv[i] >= 0.0f) ? 0x01u : 0xFFu;
  uint2 pk;
  pk.x = (unsigned)s[0] | ((unsigned)s[1] << 8) | ((unsigned)s[2] << 16) |
         ((unsigned)s[3] << 24);
  pk.y = (unsigned)s[4] | ((unsigned)s[5] << 8) | ((unsigned)s[6] << 16) |
         ((unsigned)s[7] << 24);
  *(uint2*)(A0 + base) = pk;
}

// Final output: A (i8 signs) -> f32 +-1.
__global__ void emit_kernel(const signed char* __restrict__ A,
                            float* __restrict__ out) {
  int t = blockIdx.x * blockDim.x + threadIdx.x;
  int base = t << 3;
  uint2 pk = *(const uint2*)(A + base);
  float4 o0, o1;
  o0.x = (pk.x & 0x80u) ? -1.0f : 1.0f;
  o0.y = (pk.x & 0x8000u) ? -1.0f : 1.0f;
  o0.z = (pk.x & 0x800000u) ? -1.0f : 1.0f;
  o0.w = (pk.x & 0x80000000u) ? -1.0f : 1.0f;
  o1.x = (pk.y & 0x80u) ? -1.0f : 1.0f;
  o1.y = (pk.y & 0x8000u) ? -1.0f : 1.0f;
  o1.z = (pk.y & 0x800000u) ? -1.0f : 1.0f;
  o1.w = (pk.y & 0x80000000u) ? -1.0f : 1.0f;
  *(float4*)(out + base) = o0;
  *(float4*)(out + base + 4) = o1;
}

// ---- schedule primitives ----
#define SCB() __builtin_amdgcn_sched_barrier(0)
#define SGB(m, n) __builtin_amdgcn_sched_group_barrier((m), (n), 0)
#define BAR() do { __builtin_amdgcn_sched_barrier(0);          \
                   __builtin_amdgcn_s_barrier();               \
                   __builtin_amdgcn_sched_barrier(0); } while (0)
#define VMW(N) do { asm volatile("s_waitcnt vmcnt(" #N ")" ::: "memory"); \
                    __builtin_amdgcn_sched_barrier(0); } while (0)
#define MMX(AF, BF, ACC)                                                      \
  _Pragma("unroll") for (int i_ = 0; i_ < 4; ++i_)                            \
  _Pragma("unroll") for (int j_ = 0; j_ < 4; ++j_)                            \
    ACC[i_][j_] = __builtin_amdgcn_mfma_i32_16x16x64_i8(                      \
        AF[i_], BF[j_], ACC[i_][j_], 0, 0, 0);
#define RD4S(DST, BASE) _Pragma("unroll")                                     \
  for (int q_ = 0; q_ < 4; ++q_)                                              \
    DST[q_] = *(const i32x4*)((BASE) + q_ * 1024);

// One tile (BK=64 i8, both levels) — R10 verbatim (ledgers in R10 notes).
#define TB(k, sC, sP, sS, CFa, CFh, PFa, PFh)                                 \
  {                                                                           \
    const int kS_ = ((k) + 3) << 6;                                           \
    RD4S(bl, (sC) + 24576 + bOff);                                            \
    if ((k) + 3 < NT) {                                                       \
      gl16(pAs + kS_, (sS) + ldsA);                                           \
      gl16(pAs2 + kS_, (sS) + ldsA + 1024);                                   \
      gl16(pBsH + kS_, (sS) + 16384 + ldsB);                                  \
      gl16(pBsL + kS_, (sS) + 24576 + ldsB);                                  \
    }                                                                         \
    if ((k) + 1 < NT) {                                                       \
      RD4S(PFa, (sP) + aOff);                                                 \
      RD4S(PFh, (sP) + 16384 + bOff);                                         \
    }                                                                         \
    MMX(CFa, CFh, acc1);                                                      \
    MMX(CFa, bl, acc2);                                                       \
    SGB(0x10, 4);                                                             \
    SGB(0x100, 2);                                                            \
    SGB(0x8, 3); SGB(0x100, 1);  SGB(0x8, 3); SGB(0x100, 1);                  \
    SGB(0x8, 3); SGB(0x100, 1);  SGB(0x8, 3); SGB(0x100, 1);                  \
    SGB(0x8, 3); SGB(0x100, 1);  SGB(0x8, 3); SGB(0x100, 1);                  \
    SGB(0x8, 3); SGB(0x100, 1);  SGB(0x8, 3); SGB(0x100, 1);                  \
    SGB(0x8, 3); SGB(0x100, 1);  SGB(0x8, 3); SGB(0x100, 1);                  \
    SGB(0x8, 2);                                                              \
    SCB();                                                                    \
    if ((k) + 3 < NT) { VMW(4); } else { VMW(0); }                            \
    BAR();                                                                    \
  }

__global__ void __launch_bounds__(512, 1)
gemm_fused_kernel(const signed char* __restrict__ A,
                  const signed char* __restrict__ Bt,
                  signed char* __restrict__ Anext,
                  int iter, int* __restrict__ chg,
                  int* __restrict__ counter,
                  int* __restrict__ suspects) {
  const int nt = blockIdx.x & 31, mt = blockIdx.x >> 5;
  // Early-exit: row-group mt is in its 2-cycle -> this block's output is
  // already in Anext (frozen). Pre-barrier, block-uniform (mt per block).
  if (iter > 0 && (((chg[iter - 1] >> mt) & 1) == 0)) return;

  __shared__ __align__(16) unsigned char sL[131072];   // 4 x 32 KB slabs
  __shared__ int bsame;
  const int tid = threadIdx.x;
  const int wave = tid >> 6, lane = tid & 63;
  const int lm = lane & 15, lk = lane >> 4;
  const int wm = wave >> 1, wn = wave & 1;             // 4M x 2N wave grid
  const int mBase = mt << 8, nBase = nt << 7;
  if (tid == 0) bsame = 1;

  // ---- staging lane constants (R10 verbatim; measured 0 conflicts) ----
  const int rl = lane >> 2;                            // 0..15 rows
  const int cs = ((((lane & 3) - ((lane >> 3) & 3)) & 3) << 4);  // i8 elems
  const signed char* pAs = A + (size_t)(mBase + (wave << 5) + rl) * NU + cs;
  const signed char* pAs2 = pAs + (size_t)16 * NU;
  const signed char* pBsH = Bt + (size_t)(nBase + (wave << 4) + rl) * KK2 + cs;
  const signed char* pBsL = pBsH + 4096;               // level-2 plane
  const int ldsA = wave << 11;                         // wave*2048 (A: 2 gl16)
  const int ldsB = wave << 10;                         // wave*1024 (B: 1 gl16)
  unsigned char* s0 = sL;
  unsigned char* s1 = s0 + 32768;
  unsigned char* s2 = s0 + 65536;
  unsigned char* s3 = s0 + 98304;

  // ---- fragment-read lane constants (R10 verbatim) ----
  const int pslot = (lk + ((lm >> 1) & 3)) & 3;
  const int aOff = (((wm << 6) + lm) << 6) + (pslot << 4);
  const int bOff = (((wn << 6) + lm) << 6) + (pslot << 4);

  i32x4 acc1[4][4] = {};                               // level-1 acc
  i32x4 acc2[4][4] = {};                               // level-2 acc
  i32x4 afA[4], bhA[4], afB[4], bhB[4], bl[4];

  // prologue: stage tiles 0,1,2 -> slabs 0,1,2; publish; prime tile 0 (set A)
  gl16(pAs, s0 + ldsA);           gl16(pAs2, s0 + ldsA + 1024);
  gl16(pBsH, s0 + 16384 + ldsB);  gl16(pBsL, s0 + 24576 + ldsB);
  gl16(pAs + 64, s1 + ldsA);          gl16(pAs2 + 64, s1 + ldsA + 1024);
  gl16(pBsH + 64, s1 + 16384 + ldsB); gl16(pBsL + 64, s1 + 24576 + ldsB);
  gl16(pAs + 128, s2 + ldsA);          gl16(pAs2 + 128, s2 + ldsA + 1024);
  gl16(pBsH + 128, s2 + 16384 + ldsB); gl16(pBsL + 128, s2 + 24576 + ldsB);
  VMW(0);
  BAR();
  RD4S(afA, s0 + aOff);
  RD4S(bhA, s0 + 16384 + bOff);
  SCB();

  for (int k = 0; k < NT; k += 4) {
    TB(k + 0, s0, s1, s3, afA, bhA, afB, bhB);
    TB(k + 1, s1, s2, s0, afB, bhB, afA, bhA);
    TB(k + 2, s2, s3, s1, afA, bhA, afB, bhB);
    TB(k + 3, s3, s0, s2, afB, bhB, afA, bhA);
  }

  // Fused sign epilogue + convergence compare. C/D layout (m89/m91,
  // dtype-independent m121-128): col=lane&15, row=(lane>>4)*4+reg.
  bool same = true;
#pragma unroll
  for (int i = 0; i < 4; ++i)
#pragma unroll
    for (int j = 0; j < 4; ++j)
#pragma unroll
      for (int r = 0; r < 4; ++r) {
        const int row = mBase + (wm << 6) + i * 16 + (lk << 2) + r;
        const int col = nBase + (wn << 6) + j * 16 + lm;
        const float h = S1 * (float)acc1[i][j][r] + S2 * (float)acc2[i][j][r];
        const signed char nv = (h >= 0.0f) ? (signed char)1 : (signed char)-1;
        const size_t idx = (size_t)row * NU + col;
        if (Anext[idx] != nv) same = false;   // old value = post-fixup A_{t-1}
        Anext[idx] = nv;
        if (fabsf(h) < THETA) {
          int sidx = atomicAdd(counter, 1);
          if (sidx < CAP) suspects[sidx] = (row << 12) | col;
        }
      }
  if (__builtin_amdgcn_ballot_w64(!same) != 0ull && lane == 0) bsame = 0;
  __syncthreads();
  if (tid == 0 && (iter == 0 || bsame == 0)) atomicOr(&chg[iter], 1 << mt);
}

// Suspects, 8 lanes per suspect. Exact f32 recompute vs ORIGINAL W; a patch
// that CHANGES the stored value marks the row-group as changed.
__global__ void fixup_kernel(const signed char* __restrict__ Acur,
                             const float* __restrict__ W,
                             signed char* __restrict__ Anext,
                             int iter, int* __restrict__ chg,
                             const int* __restrict__ counter,
                             const int* __restrict__ suspects,
                             int* __restrict__ flagOv) {
  int n = *counter;
  if (blockIdx.x == 0 && threadIdx.x == 0 && n > CAP) atomicAdd(flagOv, 1);
  n = n < CAP ? n : CAP;
  const int lane = threadIdx.x & 7;                       // panel index
  const int gid = (blockIdx.x * blockDim.x + threadIdx.x) >> 3;
  const int ngrp = (gridDim.x * blockDim.x) >> 3;
  for (int i = gid; i < n; i += ngrp) {
    int idx = suspects[i];
    int b = idx >> 12, j = idx & 4095;
    const float* wrow = W + (size_t)j * NU + lane * KC;
    const signed char* arow = Acur + (size_t)b * NU + lane * KC;
    float part = 0.0f;
    for (int k = 0; k < KC; k += 4) {
      float4 wv = *(const float4*)(wrow + k);
      unsigned av = *(const unsigned*)(arow + k);
      part += (av & 0x80u) ? -wv.x : wv.x;
      part += (av & 0x8000u) ? -wv.y : wv.y;
      part += (av & 0x800000u) ? -wv.z : wv.z;
      part += (av & 0x80000000u) ? -wv.w : wv.w;
    }
    float c = __shfl(part, 0, 8);
#pragma unroll
    for (int q = 1; q < 8; ++q) c += __shfl(part, q, 8);
    if (lane == 0) {
      const signed char ev = (c >= 0.0f) ? (signed char)1 : (signed char)-1;
      signed char* p = Anext + (size_t)b * NU + j;
      if (*p != ev) {
        *p = ev;
        atomicOr(&chg[iter], 1 << (b >> 8));
      }
    }
  }
}

// Tripwire: if the suspect list ever overflows, poison the output signature.
__global__ void assemble_kernel(float* __restrict__ out,
                                const int* __restrict__ flags) {
  if (threadIdx.x != 0 || blockIdx.x != 0) return;
  if (flags[1]) out[0] = 7777.0f;
}

extern "C" void kernel_launch(void* const* d_in, const int* in_sizes, int n_in,
                              void* d_out, int out_size, void* d_ws, size_t ws_size,
                              hipStream_t stream) {
  const float* P = (const float*)d_in[0];
  const float* W = (const float*)d_in[1];
  float* out = (float*)d_out;

  if (n_in < 2 || in_sizes[0] != NB * NU || in_sizes[1] != NU * NU ||
      out_size != NB * NU) {
    fill_kernel<<<4096, 256, 0, stream>>>(out, 9.0f);
    return;
  }
  if (ws_size < (size_t)REQ_WS) {
    fill_kernel<<<4096, 256, 0, stream>>>(out, 3.0f);
    return;
  }

  char* w = (char*)d_ws;
  signed char* Bt = (signed char*)(w + OFF_BT);
  signed char* A0 = (signed char*)(w + OFF_A0);
  signed char* A1 = (signed char*)(w + OFF_A1);
  int* suspects = (int*)(w + OFF_SUS);
  int* counters = (int*)(w + OFF_CNT);
  int* flags = counters + 128;  // [1]=suspect overflow
  int* chg = counters + 130;    // [t]=bitmask of changed row-groups (8 bits)

  hipMemsetAsync(counters, 0, 1024, stream);
  decompose_kernel<<<16384, 256, 0, stream>>>(W, Bt);
  init_kernel<<<4096, 256, 0, stream>>>(P, A0);

  for (int t = 0; t < ITERS; ++t) {
    signed char* Ain = (t & 1) ? A1 : A0;
    signed char* Aout = (t & 1) ? A0 : A1;
    gemm_fused_kernel<<<256, 512, 0, stream>>>(Ain, Bt, Aout, t, chg,
                                               &counters[t], suspects);
    fixup_kernel<<<256, 256, 0, stream>>>(Ain, W, Aout, t, chg,
                                          &counters[t], suspects, &flags[1]);
  }
  // A_100 lives in A0 (output buffer of odd t=99; frozen groups by parity).
  emit_kernel<<<4096, 256, 0, stream>>>(A0, out);
  assemble_kernel<<<1, 64, 0, stream>>>(out, flags);
}

// Round 12
// 12224.359 us; speedup vs baseline: 1.0656x; 1.0656x over previous
//
#include <hip/hip_runtime.h>
#include <stdint.h>

#define NU 4096
#define NB 2048
#define KK2 8192            // i8 bytes per Bt column: 2 levels x 4096
#define ITERS 100
#define CAP 262144
#define THETA 0.05f
#define KC 512              // host fixup k-panel (verified)
#define S1 0.03937007874f   // 5/127 — level-1 quant step
#define S2 (S1 / 254.0f)    // level-2 step; range = S1/2 exactly

// ws layout (bytes) — unchanged
#define OFF_BT   0u
#define OFF_A0   67108864u
#define OFF_A1   83886080u
#define OFF_SUS  100663296u
#define OFF_CNT  102760448u
#define REQ_WS   102761472u

// ROUND-12 — i8 two-level math (R10, verified exact via THETA+fixup) on the
// R4-proven schedule (best bench-true structure): SCB-pinned MFMA clusters
// with fragment reads BETWEEN clusters, FULL prime (all 12 reads for tile
// k+1 — af, bh, AND bl — issued during tile k into double-buffered register
// sets), NO sched_group_barrier (T19 null-to-harmful as graft), s_setprio
// around clusters (T5). Steady state: cluster-1 operands issued before the
// PREVIOUS tile's cluster-2; bl issued one barrier earlier — all compiler-
// counted lgkm waits pre-satisfied.
// Geometry: BM=256 x BN=128, 512 thr (8 waves 4Mx2N, wave-tile 64x64),
// grid 8x32 = 256 = 1 block/CU. BK=64 i8 (both levels) -> NT=64 tiles.
// 4 slabs x 32 KB (A 16K @0, B1 8K @16384, B2 8K @24576); stage 3 tiles
// ahead; VMW(4) at tile end for k+3<NT (outstanding = {k+2:4, k+3:4} ->
// retires k+2, published at the k->k+1 BAR, primed during k+1), else
// VMW(0) (tail; R10-verbatim guard, 2 rounds correct).
// SLOT SWIZZLE (R6-derived, measured 0 conflicts R6/R8/R10): logical 16B
// slot sl of row r at phys (sl+(r>>1))&3; inverse on global source col;
// ds_read pslot=(lk+((lm>>1)&3))&3.
#define NT 64

typedef int i32x4 __attribute__((ext_vector_type(4)));

__device__ __forceinline__ void gl16(const void* g, void* l) {
  __builtin_amdgcn_global_load_lds(
      (const __attribute__((address_space(1))) unsigned int*)g,
      (__attribute__((address_space(3))) unsigned int*)l, 16, 0, 0);
}

__global__ void fill_kernel(float* __restrict__ out, float v) {
  int t = blockIdx.x * blockDim.x + threadIdx.x;
  int base = t << 3;
  float4 a = make_float4(v, v, v, v);
  *(float4*)(out + base) = a;
  *(float4*)(out + base + 4) = a;
}

__device__ __forceinline__ int q127(float x, float s) {
  int v = (int)rintf(x / s);
  return v < -127 ? -127 : (v > 127 ? 127 : v);
}

// W f32 -> two i8 planes: Bt[col*8192 + k] = I1, Bt[col*8192 + 4096 + k] = I2.
__global__ void decompose_kernel(const float* __restrict__ W,
                                 signed char* __restrict__ Bt) {
  int t = blockIdx.x * blockDim.x + threadIdx.x;
  int base = t << 2;
  int j = base >> 12;
  int k = base & 4095;
  float4 w = *(const float4*)(W + (size_t)j * NU + k);
  int a0 = q127(w.x, S1), a1 = q127(w.y, S1), a2 = q127(w.z, S1), a3 = q127(w.w, S1);
  float r0 = w.x - (float)a0 * S1, r1 = w.y - (float)a1 * S1;
  float r2 = w.z - (float)a2 * S1, r3 = w.w - (float)a3 * S1;
  int b0 = q127(r0, S2), b1 = q127(r1, S2), b2 = q127(r2, S2), b3 = q127(r3, S2);
  uchar4 p1 = make_uchar4((unsigned char)a0, (unsigned char)a1,
                          (unsigned char)a2, (unsigned char)a3);
  uchar4 p2 = make_uchar4((unsigned char)b0, (unsigned char)b1,
                          (unsigned char)b2, (unsigned char)b3);
  *(uchar4*)(Bt + (size_t)j * KK2 + k) = p1;
  *(uchar4*)(Bt + (size_t)j * KK2 + 4096 + k) = p2;
}

// Initial state: P (fp32 +-1, exact) -> A0 i8 +-1.
__global__ void init_kernel(const float* __restrict__ P,
                            signed char* __restrict__ A0) {
  int t = blockIdx.x * blockDim.x + threadIdx.x;
  int base = t << 3;
  float4 a = *(const float4*)(P + base);
  float4 b = *(const float4*)(P + base + 4);
  float hv[8] = {a.x, a.y, a.z, a.w, b.x, b.y, b.z, b.w};
  unsigned char s[8];
#pragma unroll
  for (int i = 0; i < 8; ++i) s[i] = (hv[i] >= 0.0f) ? 0x01u : 0xFFu;
  uint2 pk;
  pk.x = (unsigned)s[0] | ((unsigned)s[1] << 8) | ((unsigned)s[2] << 16) |
         ((unsigned)s[3] << 24);
  pk.y = (unsigned)s[4] | ((unsigned)s[5] << 8) | ((unsigned)s[6] << 16) |
         ((unsigned)s[7] << 24);
  *(uint2*)(A0 + base) = pk;
}

// Final output: A (i8 signs) -> f32 +-1.
__global__ void emit_kernel(const signed char* __restrict__ A,
                            float* __restrict__ out) {
  int t = blockIdx.x * blockDim.x + threadIdx.x;
  int base = t << 3;
  uint2 pk = *(const uint2*)(A + base);
  float4 o0, o1;
  o0.x = (pk.x & 0x80u) ? -1.0f : 1.0f;
  o0.y = (pk.x & 0x8000u) ? -1.0f : 1.0f;
  o0.z = (pk.x & 0x800000u) ? -1.0f : 1.0f;
  o0.w = (pk.x & 0x80000000u) ? -1.0f : 1.0f;
  o1.x = (pk.y & 0x80u) ? -1.0f : 1.0f;
  o1.y = (pk.y & 0x8000u) ? -1.0f : 1.0f;
  o1.z = (pk.y & 0x800000u) ? -1.0f : 1.0f;
  o1.w = (pk.y & 0x80000000u) ? -1.0f : 1.0f;
  *(float4*)(out + base) = o0;
  *(float4*)(out + base + 4) = o1;
}

// ---- schedule primitives ----
#define SCB() __builtin_amdgcn_sched_barrier(0)
#define BAR() do { __builtin_amdgcn_sched_barrier(0);          \
                   __builtin_amdgcn_s_barrier();               \
                   __builtin_amdgcn_sched_barrier(0); } while (0)
#define VMW(N) do { asm volatile("s_waitcnt vmcnt(" #N ")" ::: "memory"); \
                    __builtin_amdgcn_sched_barrier(0); } while (0)
#define MM(AF, BF, ACC) do { __builtin_amdgcn_s_setprio(1);                  \
  _Pragma("unroll") for (int i_ = 0; i_ < 4; ++i_)                           \
  _Pragma("unroll") for (int j_ = 0; j_ < 4; ++j_)                           \
    ACC[i_][j_] = __builtin_amdgcn_mfma_i32_16x16x64_i8(                     \
        AF[i_], BF[j_], ACC[i_][j_], 0, 0, 0);                               \
  __builtin_amdgcn_s_setprio(0); } while (0)
#define RD4S(DST, BASE) _Pragma("unroll")                                     \
  for (int q_ = 0; q_ < 4; ++q_)                                              \
    DST[q_] = *(const i32x4*)((BASE) + q_ * 1024);

// One tile (BK=64 i8, both levels), R4-style schedule. sP = prime-source
// slab ((k+1)&3), sS = stage-dest slab ((k+3)&3). CF* = this tile's
// fragments (primed during k-1); PF* = next tile's, read here between the
// clusters. Guards depend only on k (block-uniform; barrier-safe).
#define TB(k, sP, sS, CFa, CFh, CFl, PFa, PFh, PFl)                           \
  {                                                                           \
    const int kS_ = ((k) + 3) << 6;                                           \
    SCB();                                                                    \
    MM(CFa, CFh, acc1);                     /* cluster 1 (level-1 B) */       \
    SCB();                                                                    \
    if ((k) + 1 < NT) {                                                       \
      RD4S(PFa, (sP) + aOff);                                                 \
      RD4S(PFh, (sP) + 16384 + bOff);                                         \
    }                                                                         \
    if ((k) + 3 < NT) {                                                       \
      gl16(pAs + kS_, (sS) + ldsA);                                           \
      gl16(pAs2 + kS_, (sS) + ldsA + 1024);                                   \
    }                                                                         \
    SCB();                                                                    \
    MM(CFa, CFl, acc2);                     /* cluster 2 (level-2 B) */       \
    SCB();                                                                    \
    if ((k) + 1 < NT) { RD4S(PFl, (sP) + 24576 + bOff); }                     \
    if ((k) + 3 < NT) {                                                       \
      gl16(pBsH + kS_, (sS) + 16384 + ldsB);                                  \
      gl16(pBsL + kS_, (sS) + 24576 + ldsB);                                  \
    }                                                                         \
    SCB();                                                                    \
    if ((k) + 3 < NT) { VMW(4); } else { VMW(0); }                            \
    BAR();                                                                    \
  }

__global__ void __launch_bounds__(512, 1)
gemm_fused_kernel(const signed char* __restrict__ A,
                  const signed char* __restrict__ Bt,
                  signed char* __restrict__ Anext,
                  int* __restrict__ counter,
                  int* __restrict__ suspects) {
  __shared__ __align__(16) unsigned char sL[131072];   // 4 x 32 KB slabs
  const int tid = threadIdx.x;
  const int wave = tid >> 6, lane = tid & 63;
  const int lm = lane & 15, lk = lane >> 4;
  const int wm = wave >> 1, wn = wave & 1;             // 4M x 2N wave grid
  const int nt = blockIdx.x & 31, mt = blockIdx.x >> 5;
  const int mBase = mt << 8, nBase = nt << 7;

  // ---- staging lane constants (R10 verbatim; measured 0 conflicts) ----
  const int rl = lane >> 2;                            // 0..15 rows
  const int cs = ((((lane & 3) - ((lane >> 3) & 3)) & 3) << 4);  // i8 elems
  const signed char* pAs = A + (size_t)(mBase + (wave << 5) + rl) * NU + cs;
  const signed char* pAs2 = pAs + (size_t)16 * NU;
  const signed char* pBsH = Bt + (size_t)(nBase + (wave << 4) + rl) * KK2 + cs;
  const signed char* pBsL = pBsH + 4096;               // level-2 plane
  const int ldsA = wave << 11;                         // wave*2048 (A: 2 gl16)
  const int ldsB = wave << 10;                         // wave*1024 (B: 1 gl16)
  unsigned char* s0 = sL;
  unsigned char* s1 = s0 + 32768;
  unsigned char* s2 = s0 + 65536;
  unsigned char* s3 = s0 + 98304;

  // ---- fragment-read lane constants (R10 verbatim) ----
  const int pslot = (lk + ((lm >> 1) & 3)) & 3;
  const int aOff = (((wm << 6) + lm) << 6) + (pslot << 4);
  const int bOff = (((wn << 6) + lm) << 6) + (pslot << 4);

  i32x4 acc1[4][4] = {};                               // level-1 acc
  i32x4 acc2[4][4] = {};                               // level-2 acc
  i32x4 afA[4], bhA[4], blA[4], afB[4], bhB[4], blB[4];

  // prologue: stage tiles 0,1,2 -> slabs 0,1,2; publish; prime tile 0 (set A)
  gl16(pAs, s0 + ldsA);           gl16(pAs2, s0 + ldsA + 1024);
  gl16(pBsH, s0 + 16384 + ldsB);  gl16(pBsL, s0 + 24576 + ldsB);
  gl16(pAs + 64, s1 + ldsA);          gl16(pAs2 + 64, s1 + ldsA + 1024);
  gl16(pBsH + 64, s1 + 16384 + ldsB); gl16(pBsL + 64, s1 + 24576 + ldsB);
  gl16(pAs + 128, s2 + ldsA);          gl16(pAs2 + 128, s2 + ldsA + 1024);
  gl16(pBsH + 128, s2 + 16384 + ldsB); gl16(pBsL + 128, s2 + 24576 + ldsB);
  VMW(0);
  BAR();
  RD4S(afA, s0 + aOff);
  RD4S(bhA, s0 + 16384 + bOff);
  RD4S(blA, s0 + 24576 + bOff);

  for (int k = 0; k < NT; k += 4) {
    TB(k + 0, s1, s3, afA, bhA, blA, afB, bhB, blB);
    TB(k + 1, s2, s0, afB, bhB, blB, afA, bhA, blA);
    TB(k + 2, s3, s1, afA, bhA, blA, afB, bhB, blB);
    TB(k + 3, s0, s2, afB, bhB, blB, afA, bhA, blA);
  }

  // Fused sign epilogue. C/D layout (m89/m91, dtype-independent m121-128):
  // col=lane&15, row=(lane>>4)*4+reg. h = S1*d1 + S2*d2.
#pragma unroll
  for (int i = 0; i < 4; ++i)
#pragma unroll
    for (int j = 0; j < 4; ++j)
#pragma unroll
      for (int r = 0; r < 4; ++r) {
        const int row = mBase + (wm << 6) + i * 16 + (lk << 2) + r;
        const int col = nBase + (wn << 6) + j * 16 + lm;
        const float h = S1 * (float)acc1[i][j][r] + S2 * (float)acc2[i][j][r];
        Anext[(size_t)row * NU + col] =
            (h >= 0.0f) ? (signed char)1 : (signed char)-1;
        if (fabsf(h) < THETA) {
          int sidx = atomicAdd(counter, 1);
          if (sidx < CAP) suspects[sidx] = (row << 12) | col;
        }
      }
}

// Suspects, 8 lanes per suspect. Exact f32 recompute vs ORIGINAL W.
__global__ void fixup_kernel(const signed char* __restrict__ Acur,
                             const float* __restrict__ W,
                             signed char* __restrict__ Anext,
                             const int* __restrict__ counter,
                             const int* __restrict__ suspects,
                             int* __restrict__ flagOv) {
  int n = *counter;
  if (blockIdx.x == 0 && threadIdx.x == 0 && n > CAP) atomicAdd(flagOv, 1);
  n = n < CAP ? n : CAP;
  const int lane = threadIdx.x & 7;                       // panel index
  const int gid = (blockIdx.x * blockDim.x + threadIdx.x) >> 3;
  const int ngrp = (gridDim.x * blockDim.x) >> 3;
  for (int i = gid; i < n; i += ngrp) {
    int idx = suspects[i];
    int b = idx >> 12, j = idx & 4095;
    const float* wrow = W + (size_t)j * NU + lane * KC;
    const signed char* arow = Acur + (size_t)b * NU + lane * KC;
    float part = 0.0f;
    for (int k = 0; k < KC; k += 4) {
      float4 wv = *(const float4*)(wrow + k);
      unsigned av = *(const unsigned*)(arow + k);
      part += (av & 0x80u) ? -wv.x : wv.x;
      part += (av & 0x8000u) ? -wv.y : wv.y;
      part += (av & 0x800000u) ? -wv.z : wv.z;
      part += (av & 0x80000000u) ? -wv.w : wv.w;
    }
    float c = __shfl(part, 0, 8);
#pragma unroll
    for (int q = 1; q < 8; ++q) c += __shfl(part, q, 8);
    if (lane == 0) {
      Anext[(size_t)b * NU + j] = (c >= 0.0f) ? (signed char)1 : (signed char)-1;
    }
  }
}

// Tripwire: if the suspect list ever overflows, poison the output signature.
__global__ void assemble_kernel(float* __restrict__ out,
                                const int* __restrict__ flags) {
  if (threadIdx.x != 0 || blockIdx.x != 0) return;
  if (flags[1]) out[0] = 7777.0f;
}

extern "C" void kernel_launch(void* const* d_in, const int* in_sizes, int n_in,
                              void* d_out, int out_size, void* d_ws, size_t ws_size,
                              hipStream_t stream) {
  const float* P = (const float*)d_in[0];
  const float* W = (const float*)d_in[1];
  float* out = (float*)d_out;

  if (n_in < 2 || in_sizes[0] != NB * NU || in_sizes[1] != NU * NU ||
      out_size != NB * NU) {
    fill_kernel<<<4096, 256, 0, stream>>>(out, 9.0f);
    return;
  }
  if (ws_size < (size_t)REQ_WS) {
    fill_kernel<<<4096, 256, 0, stream>>>(out, 3.0f);
    return;
  }

  char* w = (char*)d_ws;
  signed char* Bt = (signed char*)(w + OFF_BT);
  signed char* A0 = (signed char*)(w + OFF_A0);
  signed char* A1 = (signed char*)(w + OFF_A1);
  int* suspects = (int*)(w + OFF_SUS);
  int* counters = (int*)(w + OFF_CNT);
  int* flags = counters + 128;  // [1]=suspect overflow

  hipMemsetAsync(counters, 0, 1024, stream);
  decompose_kernel<<<16384, 256, 0, stream>>>(W, Bt);
  init_kernel<<<4096, 256, 0, stream>>>(P, A0);

  for (int t = 0; t < ITERS; ++t) {
    signed char* Ain = (t & 1) ? A1 : A0;
    signed char* Aout = (t & 1) ? A0 : A1;
    gemm_fused_kernel<<<256, 512, 0, stream>>>(Ain, Bt, Aout,
                                               &counters[t], suspects);
    fixup_kernel<<<256, 256, 0, stream>>>(Ain, W, Aout,
                                          &counters[t], suspects, &flags[1]);
  }
  // A_100 lives in A0 (output buffer of odd t=99).
  emit_kernel<<<4096, 256, 0, stream>>>(A0, out);
  assemble_kernel<<<1, 64, 0, stream>>>(out, flags);
}

// Round 13
// 9118.147 us; speedup vs baseline: 1.4287x; 1.3407x over previous
//
#include <hip/hip_runtime.h>
#include <stdint.h>

#define NU 4096
#define NB 2048
#define KK2 8192            // i8 bytes per Bt column: 2 levels x 4096
#define ITERS 100
#define CAP 262144
#define THETA 0.05f
#define KC 512              // host fixup k-panel (verified)
#define S1 0.03937007874f   // 5/127 — level-1 quant step
#define S2 (S1 / 254.0f)    // level-2 step; range = S1/2 exactly

// ws layout (bytes) — unchanged
#define OFF_BT   0u
#define OFF_A0   67108864u
#define OFF_A1   83886080u
#define OFF_SUS  100663296u
#define OFF_CNT  102760448u
#define REQ_WS   102761472u

// ROUND-13 — R12 i8 core with a 5-SLAB, STAGE-4-AHEAD pipeline (160 KB LDS,
// full CU allotment; 147 KB static precedent ran in R1, AITER attn uses 160).
// Diagnosis: R9->R10 halved all per-tile instruction counts but time fell
// only 9% -> the dominant per-tile cost is WAIT (~60% of tile), and the one
// wait whose distance has never exceeded ~1 tile is the staging VMW. Deepen:
// during tile j issue batch j+4 into slab (j+4)%5. End of tile k outstanding
// = batches {k+2,k+3,k+4} = 12 -> VMW(8) retires batch k+2, ISSUED DURING
// TILE k-2 (~2 full tiles ~8000 cyc before the wait — covers congested
// L2/L3 latency), published at the k->k+1 BAR, primed during k+1. Tail:
// k=NT-4 -> VMW(4); k>=NT-3 -> VMW(0). Slab WAR: slab of tile m last read
// by primes during m-1 (retired pre-barrier via compiler lgkm), restaged
// during m+1 (post-barrier) — one publishing barrier apart. s_setprio
// dropped (m190: mildly harmful on lockstep GEMM). All else R12-verbatim:
// BM=256xBN=128, 512 thr (8 waves 4Mx2N), grid 256 = 1 block/CU, BK=64 i8
// (two levels, A read/staged once), slab 32 KB (A 16K @0, B1 @16384,
// B2 @24576), SCB-pinned clusters, full register prime of tile k+1.
// SLOT SWIZZLE (measured 0 conflicts R6/R8/R10/R12): logical 16B slot sl of
// row r at phys (sl+(r>>1))&3; inverse on global source col; ds_read
// pslot=(lk+((lm>>1)&3))&3.
#define NT 64

typedef int i32x4 __attribute__((ext_vector_type(4)));

__device__ __forceinline__ void gl16(const void* g, void* l) {
  __builtin_amdgcn_global_load_lds(
      (const __attribute__((address_space(1))) unsigned int*)g,
      (__attribute__((address_space(3))) unsigned int*)l, 16, 0, 0);
}

__global__ void fill_kernel(float* __restrict__ out, float v) {
  int t = blockIdx.x * blockDim.x + threadIdx.x;
  int base = t << 3;
  float4 a = make_float4(v, v, v, v);
  *(float4*)(out + base) = a;
  *(float4*)(out + base + 4) = a;
}

__device__ __forceinline__ int q127(float x, float s) {
  int v = (int)rintf(x / s);
  return v < -127 ? -127 : (v > 127 ? 127 : v);
}

// W f32 -> two i8 planes: Bt[col*8192 + k] = I1, Bt[col*8192 + 4096 + k] = I2.
__global__ void decompose_kernel(const float* __restrict__ W,
                                 signed char* __restrict__ Bt) {
  int t = blockIdx.x * blockDim.x + threadIdx.x;
  int base = t << 2;
  int j = base >> 12;
  int k = base & 4095;
  float4 w = *(const float4*)(W + (size_t)j * NU + k);
  int a0 = q127(w.x, S1), a1 = q127(w.y, S1), a2 = q127(w.z, S1), a3 = q127(w.w, S1);
  float r0 = w.x - (float)a0 * S1, r1 = w.y - (float)a1 * S1;
  float r2 = w.z - (float)a2 * S1, r3 = w.w - (float)a3 * S1;
  int b0 = q127(r0, S2), b1 = q127(r1, S2), b2 = q127(r2, S2), b3 = q127(r3, S2);
  uchar4 p1 = make_uchar4((unsigned char)a0, (unsigned char)a1,
                          (unsigned char)a2, (unsigned char)a3);
  uchar4 p2 = make_uchar4((unsigned char)b0, (unsigned char)b1,
                          (unsigned char)b2, (unsigned char)b3);
  *(uchar4*)(Bt + (size_t)j * KK2 + k) = p1;
  *(uchar4*)(Bt + (size_t)j * KK2 + 4096 + k) = p2;
}

// Initial state: P (fp32 +-1, exact) -> A0 i8 +-1.
__global__ void init_kernel(const float* __restrict__ P,
                            signed char* __restrict__ A0) {
  int t = blockIdx.x * blockDim.x + threadIdx.x;
  int base = t << 3;
  float4 a = *(const float4*)(P + base);
  float4 b = *(const float4*)(P + base + 4);
  float hv[8] = {a.x, a.y, a.z, a.w, b.x, b.y, b.z, b.w};
  unsigned char s[8];
#pragma unroll
  for (int i = 0; i < 8; ++i) s[i] = (hv[i] >= 0.0f) ? 0x01u : 0xFFu;
  uint2 pk;
  pk.x = (unsigned)s[0] | ((unsigned)s[1] << 8) | ((unsigned)s[2] << 16) |
         ((unsigned)s[3] << 24);
  pk.y = (unsigned)s[4] | ((unsigned)s[5] << 8) | ((unsigned)s[6] << 16) |
         ((unsigned)s[7] << 24);
  *(uint2*)(A0 + base) = pk;
}

// Final output: A (i8 signs) -> f32 +-1.
__global__ void emit_kernel(const signed char* __restrict__ A,
                            float* __restrict__ out) {
  int t = blockIdx.x * blockDim.x + threadIdx.x;
  int base = t << 3;
  uint2 pk = *(const uint2*)(A + base);
  float4 o0, o1;
  o0.x = (pk.x & 0x80u) ? -1.0f : 1.0f;
  o0.y = (pk.x & 0x8000u) ? -1.0f : 1.0f;
  o0.z = (pk.x & 0x800000u) ? -1.0f : 1.0f;
  o0.w = (pk.x & 0x80000000u) ? -1.0f : 1.0f;
  o1.x = (pk.y & 0x80u) ? -1.0f : 1.0f;
  o1.y = (pk.y & 0x8000u) ? -1.0f : 1.0f;
  o1.z = (pk.y & 0x800000u) ? -1.0f : 1.0f;
  o1.w = (pk.y & 0x80000000u) ? -1.0f : 1.0f;
  *(float4*)(out + base) = o0;
  *(float4*)(out + base + 4) = o1;
}

// ---- schedule primitives ----
#define SCB() __builtin_amdgcn_sched_barrier(0)
#define BAR() do { __builtin_amdgcn_sched_barrier(0);          \
                   __builtin_amdgcn_s_barrier();               \
                   __builtin_amdgcn_sched_barrier(0); } while (0)
#define VMW(N) do { asm volatile("s_waitcnt vmcnt(" #N ")" ::: "memory"); \
                    __builtin_amdgcn_sched_barrier(0); } while (0)
#define MMX(AF, BF, ACC)                                                      \
  _Pragma("unroll") for (int i_ = 0; i_ < 4; ++i_)                            \
  _Pragma("unroll") for (int j_ = 0; j_ < 4; ++j_)                            \
    ACC[i_][j_] = __builtin_amdgcn_mfma_i32_16x16x64_i8(                      \
        AF[i_], BF[j_], ACC[i_][j_], 0, 0, 0);
#define RD4S(DST, BASE) _Pragma("unroll")                                     \
  for (int q_ = 0; q_ < 4; ++q_)                                              \
    DST[q_] = *(const i32x4*)((BASE) + q_ * 1024);

// One tile (BK=64 i8, both levels), R12 schedule + 5-slab rotation.
// sp0 = compute slab (tile k), sp1 = prime source (tile k+1), sp4 = stage
// dest (tile k+4). Pointers rotate at tile end. Guards depend only on k.
#define TB(k, CFa, CFh, CFl, PFa, PFh, PFl)                                   \
  {                                                                           \
    const int kS_ = ((k) + 4) << 6;                                           \
    SCB();                                                                    \
    MMX(CFa, CFh, acc1);                    /* cluster 1 (level-1 B) */       \
    SCB();                                                                    \
    if ((k) + 1 < NT) {                                                       \
      RD4S(PFa, sp1 + aOff);                                                  \
      RD4S(PFh, sp1 + 16384 + bOff);                                          \
    }                                                                         \
    if ((k) + 4 < NT) {                                                       \
      gl16(pAs + kS_, sp4 + ldsA);                                            \
      gl16(pAs2 + kS_, sp4 + ldsA + 1024);                                    \
    }                                                                         \
    SCB();                                                                    \
    MMX(CFa, CFl, acc2);                    /* cluster 2 (level-2 B) */       \
    SCB();                                                                    \
    if ((k) + 1 < NT) { RD4S(PFl, sp1 + 24576 + bOff); }                      \
    if ((k) + 4 < NT) {                                                       \
      gl16(pBsH + kS_, sp4 + 16384 + ldsB);                                   \
      gl16(pBsL + kS_, sp4 + 24576 + ldsB);                                   \
    }                                                                         \
    SCB();                                                                    \
    if ((k) < NT - 4) { VMW(8); }                                             \
    else if ((k) == NT - 4) { VMW(4); }                                       \
    else { VMW(0); }                                                          \
    BAR();                                                                    \
    unsigned char* r_ = sp0;                                                  \
    sp0 = sp1; sp1 = sp2; sp2 = sp3; sp3 = sp4; sp4 = r_;                     \
  }

__global__ void __launch_bounds__(512, 1)
gemm_fused_kernel(const signed char* __restrict__ A,
                  const signed char* __restrict__ Bt,
                  signed char* __restrict__ Anext,
                  int* __restrict__ counter,
                  int* __restrict__ suspects) {
  __shared__ __align__(16) unsigned char sL[163840];   // 5 x 32 KB slabs
  const int tid = threadIdx.x;
  const int wave = tid >> 6, lane = tid & 63;
  const int lm = lane & 15, lk = lane >> 4;
  const int wm = wave >> 1, wn = wave & 1;             // 4M x 2N wave grid
  const int nt = blockIdx.x & 31, mt = blockIdx.x >> 5;
  const int mBase = mt << 8, nBase = nt << 7;

  // ---- staging lane constants (R12 verbatim; measured 0 conflicts) ----
  const int rl = lane >> 2;                            // 0..15 rows
  const int cs = ((((lane & 3) - ((lane >> 3) & 3)) & 3) << 4);  // i8 elems
  const signed char* pAs = A + (size_t)(mBase + (wave << 5) + rl) * NU + cs;
  const signed char* pAs2 = pAs + (size_t)16 * NU;
  const signed char* pBsH = Bt + (size_t)(nBase + (wave << 4) + rl) * KK2 + cs;
  const signed char* pBsL = pBsH + 4096;               // level-2 plane
  const int ldsA = wave << 11;                         // wave*2048 (A: 2 gl16)
  const int ldsB = wave << 10;                         // wave*1024 (B: 1 gl16)
  unsigned char* sp0 = sL;
  unsigned char* sp1 = sL + 32768;
  unsigned char* sp2 = sL + 65536;
  unsigned char* sp3 = sL + 98304;
  unsigned char* sp4 = sL + 131072;

  // ---- fragment-read lane constants (R12 verbatim) ----
  const int pslot = (lk + ((lm >> 1) & 3)) & 3;
  const int aOff = (((wm << 6) + lm) << 6) + (pslot << 4);
  const int bOff = (((wn << 6) + lm) << 6) + (pslot << 4);

  i32x4 acc1[4][4] = {};                               // level-1 acc
  i32x4 acc2[4][4] = {};                               // level-2 acc
  i32x4 afA[4], bhA[4], blA[4], afB[4], bhB[4], blB[4];

  // prologue: stage tiles 0..3 -> slabs 0..3; publish; prime tile 0 (set A)
  gl16(pAs, sp0 + ldsA);           gl16(pAs2, sp0 + ldsA + 1024);
  gl16(pBsH, sp0 + 16384 + ldsB);  gl16(pBsL, sp0 + 24576 + ldsB);
  gl16(pAs + 64, sp1 + ldsA);          gl16(pAs2 + 64, sp1 + ldsA + 1024);
  gl16(pBsH + 64, sp1 + 16384 + ldsB); gl16(pBsL + 64, sp1 + 24576 + ldsB);
  gl16(pAs + 128, sp2 + ldsA);          gl16(pAs2 + 128, sp2 + ldsA + 1024);
  gl16(pBsH + 128, sp2 + 16384 + ldsB); gl16(pBsL + 128, sp2 + 24576 + ldsB);
  gl16(pAs + 192, sp3 + ldsA);          gl16(pAs2 + 192, sp3 + ldsA + 1024);
  gl16(pBsH + 192, sp3 + 16384 + ldsB); gl16(pBsL + 192, sp3 + 24576 + ldsB);
  VMW(0);
  BAR();
  RD4S(afA, sp0 + aOff);
  RD4S(bhA, sp0 + 16384 + bOff);
  RD4S(blA, sp0 + 24576 + bOff);

  for (int k = 0; k < NT; k += 2) {
    TB(k + 0, afA, bhA, blA, afB, bhB, blB);
    TB(k + 1, afB, bhB, blB, afA, bhA, blA);
  }

  // Fused sign epilogue. C/D layout (m89/m91, dtype-independent m121-128):
  // col=lane&15, row=(lane>>4)*4+reg. h = S1*d1 + S2*d2.
#pragma unroll
  for (int i = 0; i < 4; ++i)
#pragma unroll
    for (int j = 0; j < 4; ++j)
#pragma unroll
      for (int r = 0; r < 4; ++r) {
        const int row = mBase + (wm << 6) + i * 16 + (lk << 2) + r;
        const int col = nBase + (wn << 6) + j * 16 + lm;
        const float h = S1 * (float)acc1[i][j][r] + S2 * (float)acc2[i][j][r];
        Anext[(size_t)row * NU + col] =
            (h >= 0.0f) ? (signed char)1 : (signed char)-1;
        if (fabsf(h) < THETA) {
          int sidx = atomicAdd(counter, 1);
          if (sidx < CAP) suspects[sidx] = (row << 12) | col;
        }
      }
}

// Suspects, 8 lanes per suspect. Exact f32 recompute vs ORIGINAL W.
__global__ void fixup_kernel(const signed char* __restrict__ Acur,
                             const float* __restrict__ W,
                             signed char* __restrict__ Anext,
                             const int* __restrict__ counter,
                             const int* __restrict__ suspects,
                             int* __restrict__ flagOv) {
  int n = *counter;
  if (blockIdx.x == 0 && threadIdx.x == 0 && n > CAP) atomicAdd(flagOv, 1);
  n = n < CAP ? n : CAP;
  const int lane = threadIdx.x & 7;                       // panel index
  const int gid = (blockIdx.x * blockDim.x + threadIdx.x) >> 3;
  const int ngrp = (gridDim.x * blockDim.x) >> 3;
  for (int i = gid; i < n; i += ngrp) {
    int idx = suspects[i];
    int b = idx >> 12, j = idx & 4095;
    const float* wrow = W + (size_t)j * NU + lane * KC;
    const signed char* arow = Acur + (size_t)b * NU + lane * KC;
    float part = 0.0f;
    for (int k = 0; k < KC; k += 4) {
      float4 wv = *(const float4*)(wrow + k);
      unsigned av = *(const unsigned*)(arow + k);
      part += (av & 0x80u) ? -wv.x : wv.x;
      part += (av & 0x8000u) ? -wv.y : wv.y;
      part += (av & 0x800000u) ? -wv.z : wv.z;
      part += (av & 0x80000000u) ? -wv.w : wv.w;
    }
    float c = __shfl(part, 0, 8);
#pragma unroll
    for (int q = 1; q < 8; ++q) c += __shfl(part, q, 8);
    if (lane == 0) {
      Anext[(size_t)b * NU + j] = (c >= 0.0f) ? (signed char)1 : (signed char)-1;
    }
  }
}

// Tripwire: if the suspect list ever overflows, poison the output signature.
__global__ void assemble_kernel(float* __restrict__ out,
                                const int* __restrict__ flags) {
  if (threadIdx.x != 0 || blockIdx.x != 0) return;
  if (flags[1]) out[0] = 7777.0f;
}

extern "C" void kernel_launch(void* const* d_in, const int* in_sizes, int n_in,
                              void* d_out, int out_size, void* d_ws, size_t ws_size,
                              hipStream_t stream) {
  const float* P = (const float*)d_in[0];
  const float* W = (const float*)d_in[1];
  float* out = (float*)d_out;

  if (n_in < 2 || in_sizes[0] != NB * NU || in_sizes[1] != NU * NU ||
      out_size != NB * NU) {
    fill_kernel<<<4096, 256, 0, stream>>>(out, 9.0f);
    return;
  }
  if (ws_size < (size_t)REQ_WS) {
    fill_kernel<<<4096, 256, 0, stream>>>(out, 3.0f);
    return;
  }

  char* w = (char*)d_ws;
  signed char* Bt = (signed char*)(w + OFF_BT);
  signed char* A0 = (signed char*)(w + OFF_A0);
  signed char* A1 = (signed char*)(w + OFF_A1);
  int* suspects = (int*)(w + OFF_SUS);
  int* counters = (int*)(w + OFF_CNT);
  int* flags = counters + 128;  // [1]=suspect overflow

  hipMemsetAsync(counters, 0, 1024, stream);
  decompose_kernel<<<16384, 256, 0, stream>>>(W, Bt);
  init_kernel<<<4096, 256, 0, stream>>>(P, A0);

  for (int t = 0; t < ITERS; ++t) {
    signed char* Ain = (t & 1) ? A1 : A0;
    signed char* Aout = (t & 1) ? A0 : A1;
    gemm_fused_kernel<<<256, 512, 0, stream>>>(Ain, Bt, Aout,
                                               &counters[t], suspects);
    fixup_kernel<<<256, 256, 0, stream>>>(Ain, W, Aout,
                                          &counters[t], suspects, &flags[1]);
  }
  // A_100 lives in A0 (output buffer of odd t=99).
  emit_kernel<<<4096, 256, 0, stream>>>(A0, out);
  assemble_kernel<<<1, 64, 0, stream>>>(out, flags);
}